// Round 11
// baseline (305.274 us; speedup 1.0000x reference)
//
#include <hip/hip_runtime.h>

// MHA fwd: B=4, T=2048, D=1024, H=16, DK=64. Inputs/outputs f32 (flag-detected), compute bf16 MFMA.
// d_in: 0=x, 1=mask(ignored), 2=wq, 3=bq, 4=wk, 5=bk, 6=wv, 7=bv, 8=wo, 9=bo

typedef short s16x8 __attribute__((ext_vector_type(8)));
typedef short s16x4 __attribute__((ext_vector_type(4)));
typedef float f32x4 __attribute__((ext_vector_type(4)));
typedef unsigned int u32x2 __attribute__((ext_vector_type(2)));
typedef unsigned short u16x4 __attribute__((ext_vector_type(4)));

static __device__ __forceinline__ float bf2f(unsigned short u) {
    return __uint_as_float(((unsigned int)u) << 16);
}
static __device__ __forceinline__ unsigned short f2bf(float f) {
    unsigned int x = __float_as_uint(f);
    unsigned int r = x + 0x7fffu + ((x >> 16) & 1u);  // RTNE
    return (unsigned short)(r >> 16);
}

static __device__ __forceinline__ void gload_lds16(const short* g, short* l) {
    __builtin_amdgcn_global_load_lds((__attribute__((address_space(1))) void*)g,
                                     (__attribute__((address_space(3))) void*)l, 16, 0, 0);
}

// packed f32x2 -> bf16x2 (RTNE); src0 -> low 16 bits
static __device__ __forceinline__ unsigned int cvt_pk_bf16(float a, float b) {
    unsigned int r;
    asm("v_cvt_pk_bf16_f32 %0, %1, %2" : "=v"(r) : "v"(a), "v"(b));
    return r;
}

// raw v_exp_f32 (exp2): libm exp2f w/o fast-math emits ~7 extra VALU ops of denorm/range
// fixup per call; attention P in [0,2^8] only needs flush-to-zero semantics. -inf -> 0.
static __device__ __forceinline__ float fexp2(float x) {
    float r;
    asm("v_exp_f32 %0, %1" : "=v"(r) : "v"(x));
    return r;
}

// ---- fused prep: dtype-detect (per-block, redundant, L2-broadcast) + x-convert (x4 vec)
//      + biases + 4 weight transposes, ONE launch; block 0 publishes flag for gemm2 ----
__global__ __launch_bounds__(256) void prep(const void* __restrict__ x,
                                            const void* __restrict__ b0, const void* __restrict__ b1,
                                            const void* __restrict__ b2, const void* __restrict__ b3,
                                            const void* __restrict__ w0, const void* __restrict__ w1,
                                            const void* __restrict__ w2, const void* __restrict__ w3,
                                            unsigned short* __restrict__ xb,
                                            unsigned short* __restrict__ bb,
                                            unsigned short* __restrict__ wT,
                                            int* __restrict__ flag) {
    __shared__ unsigned short t[32][33];
    __shared__ int sflag;
    int bid = blockIdx.x, tid = threadIdx.x;

    // detect: first 4096 ushorts of x; bf16-reinterpreted f32 mantissas show huge magnitudes
    {
        const unsigned short* xs = (const unsigned short*)x;
        bool big = false;
        for (int k = 0; k < 16; ++k) {
            float v = bf2f(xs[tid * 16 + k]);
            big |= !(fabsf(v) < 1e10f);
        }
        unsigned long long m = __ballot(big);
        if (tid == 0) sflag = 0;
        __syncthreads();
        if ((tid & 63) == 0 && m != 0ull) sflag = 1;   // benign same-value race
        __syncthreads();
    }
    int f = sflag;
    if (bid == 0 && tid == 0) *flag = f;               // for gemm2's f32-out path

    if (bid < 8192) {                       // x: 8.4M elems, float4/ushort4 per thread
        int i = bid * 256 + tid;
        u16x4 o;
        if (f) {
            float4 v = ((const float4*)x)[i];
            o[0] = f2bf(v.x); o[1] = f2bf(v.y); o[2] = f2bf(v.z); o[3] = f2bf(v.w);
        } else {
            o = ((const u16x4*)x)[i];
        }
        ((u16x4*)xb)[i] = o;
    } else if (bid < 8208) {                // biases: 16 blocks x 256 = 4096
        int i = (bid - 8192) * 256 + tid;
        const void* src = (i < 1024) ? b0 : (i < 2048 ? b1 : (i < 3072 ? b2 : b3));
        int k = i & 1023;
        bb[i] = f ? f2bf(((const float*)src)[k]) : ((const unsigned short*)src)[k];
    } else {                                // weight transpose: 4 x 1024 tiles
        int tz = bid - 8208;
        int z = tz >> 10, tile = tz & 1023;
        const void* src = (z == 0) ? w0 : (z == 1 ? w1 : (z == 2 ? w2 : w3));
        unsigned short* dst = wT + (size_t)z * 1024 * 1024;
        int xx = tid & 31, yy = tid >> 5;   // 32 x 8
        int n0 = (tile & 31) * 32, k0 = (tile >> 5) * 32;
        for (int j = 0; j < 32; j += 8) {
            size_t idx = (size_t)(k0 + yy + j) * 1024 + n0 + xx;
            t[yy + j][xx] = f ? f2bf(((const float*)src)[idx]) : ((const unsigned short*)src)[idx];
        }
        __syncthreads();
        for (int j = 0; j < 32; j += 8) dst[(size_t)(n0 + yy + j) * 1024 + k0 + xx] = t[xx][yy + j];
    }
}

// ---- GEMM (128-tile, R7-proven pipelined schedule): C = A.Bt + bias ----
// LDS double-buffered; STAGE(t+1) issued BEFORE compute(t); ONE __syncthreads per K-step.
// XOR-swizzled LDS (slot = chunk ^ (row&7)), pre-swizzled global source.
// NEW (R11):
//  * T1 XCD swizzle (bijective, nwg%8==0): each XCD gets contiguous n-panels -> B-panel
//    (0.75MB) becomes L2-resident per XCD. gemm1 is L2/L3-BW-bound (staging needs ~127TB/s
//    vs 34.5 L2), so locality is the lever.
//  * Coalesced V epilogue: the old 8B-stores-at-4KB-stride scatter put each lane's store on
//    its own 64B line (R9 gemm256: WRITE_SIZE 79MB vs 48MB data). V-blocks (n0>=2048, whole
//    tile) now transpose via the dead As/Bs LDS and emit 128B-contiguous runs.
__global__ __launch_bounds__(256) void gemm_bf16(const short* __restrict__ A,
                                                 const short* __restrict__ Bt,
                                                 void* __restrict__ C,
                                                 short* __restrict__ vt,
                                                 const unsigned short* __restrict__ bq,
                                                 const unsigned short* __restrict__ bk,
                                                 const unsigned short* __restrict__ bv,
                                                 int K, int ldc,
                                                 const int* __restrict__ flag, int f32out,
                                                 int scale_q, int fuse_v) {
    __shared__ __align__(16) short As[2][128][64];
    __shared__ __align__(16) short Bs[2][128][64];
    int tid = threadIdx.x;
    int wid = tid >> 6, lane = tid & 63, quad = lane >> 4, l16 = lane & 15;
    int wm = wid & 1, wn = wid >> 1;

    // T1: XCD-contiguous remap (gridDim.x == 64 for both call sites; nwg % 8 == 0)
    int flat = blockIdx.y * 64 + blockIdx.x;
    int nwg = gridDim.x * gridDim.y;
    int swz = (flat & 7) * (nwg >> 3) + (flat >> 3);
    int m0 = (swz & 63) * 128, n0 = (swz >> 6) * 128;
    bool wf = f32out && (*flag != 0);

    int srow = lane >> 3;                  // 0..7: row within the 8-row stage chunk
    int schunk = (lane & 7) ^ srow;        // pre-swizzled source chunk for this LDS slot
    const short* Ag = A  + (size_t)(m0 + wid * 32 + srow) * K + schunk * 8;
    const short* Bg = Bt + (size_t)(n0 + wid * 32 + srow) * K + schunk * 8;

    f32x4 acc[4][4] = {};
    int nt = K >> 6;

#pragma unroll
    for (int c = 0; c < 4; ++c) {
        gload_lds16(Ag + c * 8 * K, &As[0][wid * 32 + c * 8][0]);
        gload_lds16(Bg + c * 8 * K, &Bs[0][wid * 32 + c * 8][0]);
    }
    __syncthreads();

    for (int t = 0; t < nt; ++t) {
        if (t + 1 < nt) {                   // issue next-tile loads FIRST (hide under MFMA)
            int bu = (t + 1) & 1;
            int kof = (t + 1) * 64;
#pragma unroll
            for (int c = 0; c < 4; ++c) {
                gload_lds16(Ag + kof + c * 8 * K, &As[bu][wid * 32 + c * 8][0]);
                gload_lds16(Bg + kof + c * 8 * K, &Bs[bu][wid * 32 + c * 8][0]);
            }
        }
        const short (*Ab)[64] = As[t & 1];
#pragma unroll
        for (int kk = 0; kk < 2; ++kk) {    // two K=32 slices of the BK=64 tile
            s16x8 a[4], b[4];
#pragma unroll
            for (int i = 0; i < 4; ++i) {
                int row = wm * 64 + i * 16 + l16;
                a[i] = *(const s16x8*)&Ab[row][(((kk << 2) + quad) ^ (row & 7)) << 3];
            }
#pragma unroll
            for (int j = 0; j < 4; ++j) {
                int row = wn * 64 + j * 16 + l16;
                b[j] = *(const s16x8*)&Bs[t & 1][row][(((kk << 2) + quad) ^ (row & 7)) << 3];
            }
            __builtin_amdgcn_s_setprio(1);
#pragma unroll
            for (int i = 0; i < 4; ++i)
#pragma unroll
                for (int j = 0; j < 4; ++j)
                    acc[i][j] = __builtin_amdgcn_mfma_f32_16x16x32_bf16(a[i], b[j], acc[i][j], 0, 0, 0);
            __builtin_amdgcn_s_setprio(0);
        }
        __syncthreads();                    // single barrier/K-step: drains stage(t+1) + sync
    }

    if (fuse_v && n0 >= 2048) {
        // Whole tile is V. Transpose 128x128 via dead As/Bs (two 64x136 halves, 17.4KB each;
        // stride 136 shorts: 16B-aligned rows, write conflicts ~2-way). Then 128B-contiguous
        // stores into vt[(b*16+h)*64+dk][t] -- full-line HBM writes (was 8B per 64B line).
        short* vtl = (wn == 0) ? (short*)As : (short*)Bs;   // half by wn (cols 0-63 / 64-127)
#pragma unroll
        for (int j = 0; j < 4; ++j) {
            int c = j * 16 + l16;                           // dk within half
            float bias = bf2f(bv[(n0 - 2048) + wn * 64 + c]);
#pragma unroll
            for (int i = 0; i < 4; ++i) {
                int row = wm * 64 + i * 16 + quad * 4;      // t-local 0..127
                s16x4 pk;
                for (int r = 0; r < 4; ++r) pk[r] = (short)f2bf(acc[i][j][r] + bias);
                *(s16x4*)(vtl + c * 136 + row) = pk;
            }
        }
        __syncthreads();
        int sel = tid >> 7, t2 = tid & 127;                 // sel: which 64-col half
        int c = t2 >> 1, tc = (t2 & 1) * 64;                // dk row, 64-t chunk
        const short* vs = (sel ? (const short*)Bs : (const short*)As) + c * 136 + tc;
        int hgl = ((n0 - 2048) >> 6) + sel;
        int b_ = m0 >> 11;
        short* gdst = vt + ((size_t)((b_ * 16 + hgl) * 64 + c)) * 2048 + (m0 & 2047) + tc;
#pragma unroll
        for (int e = 0; e < 8; ++e)
            ((s16x8*)gdst)[e] = ((const s16x8*)vs)[e];      // 128B contiguous per thread
    } else {
        for (int j = 0; j < 4; ++j) {
            int col = n0 + wn * 64 + j * 16 + l16;
            const unsigned short* bptr = (col < 1024) ? bq : (col < 2048 ? bk : bv);
            float bias = bf2f(bptr[col & 1023]);
            float cs = (scale_q && col < 1024) ? 0.18033688f : 1.0f;   // 1/sqrt(64)*log2(e)
            for (int i = 0; i < 4; ++i) {
                int rbase = m0 + wm * 64 + i * 16 + quad * 4;
                for (int r = 0; r < 4; ++r) {
                    float v = (acc[i][j][r] + bias) * cs;
                    size_t idx = (size_t)(rbase + r) * ldc + col;
                    if (wf) ((float*)C)[idx] = v;
                    else    ((unsigned short*)C)[idx] = f2bf(v);
                }
            }
        }
    }
}

// ---- flash attention, counted-vmcnt pipeline (T3/T4) -- R7 form (85.4us measured) ----
static __device__ __forceinline__ void stage_tiles(const short* kbase, const short* vbase,
                                                   int kt, short* Kb, short* Vb,
                                                   int wid, int lane) {
    int row = wid * 8 + (lane >> 3);            // 0..63
    int c_src = (lane & 7) ^ (lane >> 3);       // source chunk for this slot
    const short* kg = kbase + (size_t)(kt * 64 + row) * 3072 + c_src * 8;
    const short* vg = vbase + (size_t)row * 2048 + kt * 64 + c_src * 8;
    gload_lds16(kg, Kb + wid * 512);            // wave-uniform LDS base + lane*16
    gload_lds16(vg, Vb + wid * 512);
}

static __device__ __forceinline__ s16x8 lds_frag(const short* buf, int row, int cg) {
    int slot = cg ^ (row & 7);
    return *(const s16x8*)(buf + row * 64 + slot * 8);
}

// grid (64, 16): x = bh, y -> qb = 15-y (heavy-first). 8 waves x 16 q-rows.
// K/V TRIPLE-buffered; ONE raw s_barrier per K-tile; counted s_waitcnt vmcnt(2).
// SWAPPED softmax (T12); T13 defer-max; raw v_exp_f32.
__global__ __launch_bounds__(512, 4) void attn(const short* __restrict__ qkv,
                                               const short* __restrict__ vt,
                                               unsigned short* __restrict__ y) {
    __shared__ __align__(16) short Kbuf[3][64 * 64];
    __shared__ __align__(16) short Vbuf[3][64 * 64];
    __shared__ __align__(16) short Ps[8][16 * 68];
    int tid = threadIdx.x;
    int wid = tid >> 6, lane = tid & 63, quad = lane >> 4, l16 = lane & 15;
    int bh = blockIdx.x, b = bh >> 4, h = bh & 15;
    const short* kbase = qkv + (size_t)b * 2048 * 3072 + 1024 + h * 64;
    const short* vbase = vt + (size_t)bh * 64 * 2048;
    short* PsW = &Ps[wid][0];

    s16x8 ones;
    for (int e = 0; e < 8; ++e) ones[e] = (short)0x3F80;   // bf16 1.0

    int qb = 15 - (int)blockIdx.y;              // heavy-first dispatch order
    int ktmax = 2 * qb + 1;
    int kmax_w = 2 * qb + (wid >> 2);           // causal limit for this wave's rows

    const short* qp = qkv + (size_t)(b * 2048 + qb * 128 + wid * 16 + l16) * 3072 + h * 64;
    s16x8 q0 = *(const s16x8*)(qp + quad * 8);
    s16x8 q1 = *(const s16x8*)(qp + 32 + quad * 8);

    float m_old = -INFINITY;                    // running max for q-row l16 (per-lane scalar)
    f32x4 lacc = {0.f, 0.f, 0.f, 0.f};
    f32x4 o[4] = {};

    stage_tiles(kbase, vbase, 0, &Kbuf[0][0], &Vbuf[0][0], wid, lane);
    stage_tiles(kbase, vbase, 1, &Kbuf[1][0], &Vbuf[1][0], wid, lane);
    int ss = 2;                                 // next stage slot
    int cc = 0;                                 // compute slot

    for (int kt = 0; kt <= ktmax; ++kt) {
        if (kt < ktmax) asm volatile("s_waitcnt vmcnt(2)" ::: "memory");
        else            asm volatile("s_waitcnt vmcnt(0)" ::: "memory");
        __builtin_amdgcn_sched_barrier(0);
        __builtin_amdgcn_s_barrier();

        if (kt + 2 <= ktmax) {
            stage_tiles(kbase, vbase, kt + 2, &Kbuf[0][0] + ss * 4096, &Vbuf[0][0] + ss * 4096,
                        wid, lane);
            ss = (ss == 2) ? 0 : ss + 1;
        }

        if (kt <= kmax_w) {                     // predicated compute; barriers stay uniform
            const short* Kb = &Kbuf[0][0] + cc * 4096;
            const short* Vb = &Vbuf[0][0] + cc * 4096;

            // S^T = K . Q^T  (A=K fragment, B=Q fragment: identical reg layouts, swapped roles)
            f32x4 s[4] = {};
            __builtin_amdgcn_s_setprio(1);
            for (int j = 0; j < 4; ++j) {
                s16x8 klo = lds_frag(Kb, j * 16 + l16, quad);
                s16x8 khi = lds_frag(Kb, j * 16 + l16, 4 + quad);
                s[j] = __builtin_amdgcn_mfma_f32_16x16x32_bf16(klo, q0, s[j], 0, 0, 0);
                s[j] = __builtin_amdgcn_mfma_f32_16x16x32_bf16(khi, q1, s[j], 0, 0, 0);
            }
            __builtin_amdgcn_s_setprio(0);

            if (kt == kmax_w) {                 // diagonal tile: mask k > q
                int qq = (wid & 3) * 16 + l16;  // q-row local to this 64-row k-tile span
                for (int j = 0; j < 4; ++j)
                    for (int r = 0; r < 4; ++r)
                        if (j * 16 + quad * 4 + r > qq) s[j][r] = -INFINITY;
            }

            // row-max: max3-friendly tree over 16 in-lane regs, then across the 4 quads
            float mj0 = fmaxf(fmaxf(s[0][0], s[0][1]), s[0][2]);   // v_max3
            mj0 = fmaxf(mj0, s[0][3]);
            float mj1 = fmaxf(fmaxf(s[1][0], s[1][1]), s[1][2]);
            mj1 = fmaxf(mj1, s[1][3]);
            float mj2 = fmaxf(fmaxf(s[2][0], s[2][1]), s[2][2]);
            mj2 = fmaxf(mj2, s[2][3]);
            float mj3 = fmaxf(fmaxf(s[3][0], s[3][1]), s[3][2]);
            mj3 = fmaxf(mj3, s[3][3]);
            float mx = fmaxf(fmaxf(fmaxf(mj0, mj1), mj2), mj3);
            mx = fmaxf(mx, __shfl_xor(mx, 16));
            mx = fmaxf(mx, __shfl_xor(mx, 32));

            // T13 defer-max: only rescale when some row grew by > 8 (log2 domain; P <= 256)
            if (__any(mx > m_old + 8.0f)) {
                float mn = fmaxf(m_old, mx);
                float alpha = fexp2(m_old - mn);    // 1 per lane
                m_old = mn;
                // O/lacc rows are quad*4+r (standard layout); alpha for row i lives in lane i
                float ar[4];
                for (int r = 0; r < 4; ++r) ar[r] = __shfl(alpha, quad * 4 + r);
                for (int r = 0; r < 4; ++r) {
                    lacc[r] *= ar[r];
                    for (int d = 0; d < 4; ++d) o[d][r] *= ar[r];
                }
            }

            // P = exp2(S - m): adjacent k in-lane -> packed bf16 pairs, one b64 store per j
            for (int j = 0; j < 4; ++j) {
                float p0 = fexp2(s[j][0] - m_old);
                float p1 = fexp2(s[j][1] - m_old);
                float p2 = fexp2(s[j][2] - m_old);
                float p3 = fexp2(s[j][3] - m_old);
                u32x2 w;
                w.x = cvt_pk_bf16(p0, p1);
                w.y = cvt_pk_bf16(p2, p3);
                *(u32x2*)(PsW + l16 * 68 + j * 16 + quad * 4) = w;   // P[q=l16][t=16j+4quad..+3]
            }

            // same-wave LDS RAW: DS ops program-ordered per wave
            s16x8 pa0 = *(const s16x8*)&PsW[l16 * 68 + quad * 8];
            s16x8 pa1 = *(const s16x8*)&PsW[l16 * 68 + 32 + quad * 8];
            __builtin_amdgcn_s_setprio(1);
            lacc = __builtin_amdgcn_mfma_f32_16x16x32_bf16(pa0, ones, lacc, 0, 0, 0);
            lacc = __builtin_amdgcn_mfma_f32_16x16x32_bf16(pa1, ones, lacc, 0, 0, 0);
            for (int d = 0; d < 4; ++d) {
                s16x8 vlo = lds_frag(Vb, d * 16 + l16, quad);
                s16x8 vhi = lds_frag(Vb, d * 16 + l16, 4 + quad);
                o[d] = __builtin_amdgcn_mfma_f32_16x16x32_bf16(pa0, vlo, o[d], 0, 0, 0);
                o[d] = __builtin_amdgcn_mfma_f32_16x16x32_bf16(pa1, vhi, o[d], 0, 0, 0);
            }
            __builtin_amdgcn_s_setprio(0);
        }
        cc = (cc == 2) ? 0 : cc + 1;
    }

    for (int r = 0; r < 4; ++r) {
        float inv = 1.f / lacc[r];
        int t = qb * 128 + wid * 16 + quad * 4 + r;
        for (int d = 0; d < 4; ++d)
            y[(size_t)(b * 2048 + t) * 1024 + h * 64 + d * 16 + l16] = f2bf(o[d][r] * inv);
    }
}

extern "C" void kernel_launch(void* const* d_in, const int* in_sizes, int n_in,
                              void* d_out, int out_size, void* d_ws, size_t ws_size,
                              hipStream_t stream) {
    (void)in_sizes; (void)n_in; (void)out_size; (void)ws_size;
    const void* x  = d_in[0];
    const void* wq = d_in[2]; const void* bq = d_in[3];
    const void* wk = d_in[4]; const void* bk = d_in[5];
    const void* wv = d_in[6]; const void* bv = d_in[7];
    const void* wo = d_in[8]; const void* bo = d_in[9];

    const size_t MB = 1024 * 1024;
    char* ws = (char*)d_ws;
    unsigned short* wT  = (unsigned short*)ws;                 // 4x[1024][1024] bf16  [0,8MB)
    short* qkv = (short*)(ws + 8 * MB);                        // [8192][3072] bf16    [8,56)
    short* vt  = (short*)(ws + 56 * MB);                       // [64][64][2048] bf16  [56,72)
    unsigned short* xb = (unsigned short*)(ws + 72 * MB);      // x as bf16 (aliases yb)
    unsigned short* yb = (unsigned short*)(ws + 72 * MB);      // attn out (after xb dead)
    unsigned short* bb = (unsigned short*)(ws + 88 * MB);      // 4x1024 bf16 biases
    int* flag = (int*)(ws + 88 * MB + 64 * 1024);

    prep<<<12304, 256, 0, stream>>>(x, bq, bk, bv, bo, wq, wk, wv, wo, xb, bb, wT, flag);

    gemm_bf16<<<dim3(64, 24), 256, 0, stream>>>((const short*)xb, (const short*)wT,
                                                qkv, vt, bb, bb + 1024, bb + 2048,
                                                1024, 3072, flag, 0, 1, 1);
    attn<<<dim3(64, 16), 512, 0, stream>>>(qkv, vt, yb);
    gemm_bf16<<<dim3(64, 8), 256, 0, stream>>>((const short*)yb, (const short*)(wT + 3072 * 1024),
                                               d_out, nullptr, bb + 3072, bb + 3072, bb + 3072,
                                               1024, 1024, flag, 1, 0, 0);
}

// Round 12
// 288.346 us; speedup vs baseline: 1.0587x; 1.0587x over previous
//
#include <hip/hip_runtime.h>

// MHA fwd: B=4, T=2048, D=1024, H=16, DK=64. Inputs/outputs f32 (flag-detected), compute bf16 MFMA.
// d_in: 0=x, 1=mask(ignored), 2=wq, 3=bq, 4=wk, 5=bk, 6=wv, 7=bv, 8=wo, 9=bo

typedef short s16x8 __attribute__((ext_vector_type(8)));
typedef short s16x4 __attribute__((ext_vector_type(4)));
typedef float f32x4 __attribute__((ext_vector_type(4)));
typedef unsigned int u32x2 __attribute__((ext_vector_type(2)));
typedef unsigned short u16x4 __attribute__((ext_vector_type(4)));

static __device__ __forceinline__ float bf2f(unsigned short u) {
    return __uint_as_float(((unsigned int)u) << 16);
}
static __device__ __forceinline__ unsigned short f2bf(float f) {
    unsigned int x = __float_as_uint(f);
    unsigned int r = x + 0x7fffu + ((x >> 16) & 1u);  // RTNE
    return (unsigned short)(r >> 16);
}

static __device__ __forceinline__ void gload_lds16(const short* g, short* l) {
    __builtin_amdgcn_global_load_lds((__attribute__((address_space(1))) void*)g,
                                     (__attribute__((address_space(3))) void*)l, 16, 0, 0);
}

// packed f32x2 -> bf16x2 (RTNE); src0 -> low 16 bits
static __device__ __forceinline__ unsigned int cvt_pk_bf16(float a, float b) {
    unsigned int r;
    asm("v_cvt_pk_bf16_f32 %0, %1, %2" : "=v"(r) : "v"(a), "v"(b));
    return r;
}

// raw v_exp_f32 (exp2): libm exp2f w/o fast-math emits ~7 extra VALU ops of denorm/range
// fixup per call; attention P in [0,2^8] only needs flush-to-zero semantics. -inf -> 0.
static __device__ __forceinline__ float fexp2(float x) {
    float r;
    asm("v_exp_f32 %0, %1" : "=v"(r) : "v"(x));
    return r;
}

// ---- fused prep: dtype-detect (per-block, redundant, L2-broadcast) + x-convert (x4 vec)
//      + biases + 4 weight transposes, ONE launch; block 0 publishes flag for gemm2 ----
__global__ __launch_bounds__(256) void prep(const void* __restrict__ x,
                                            const void* __restrict__ b0, const void* __restrict__ b1,
                                            const void* __restrict__ b2, const void* __restrict__ b3,
                                            const void* __restrict__ w0, const void* __restrict__ w1,
                                            const void* __restrict__ w2, const void* __restrict__ w3,
                                            unsigned short* __restrict__ xb,
                                            unsigned short* __restrict__ bb,
                                            unsigned short* __restrict__ wT,
                                            int* __restrict__ flag) {
    __shared__ unsigned short t[32][33];
    __shared__ int sflag;
    int bid = blockIdx.x, tid = threadIdx.x;

    // detect: first 4096 ushorts of x; bf16-reinterpreted f32 mantissas show huge magnitudes
    {
        const unsigned short* xs = (const unsigned short*)x;
        bool big = false;
        for (int k = 0; k < 16; ++k) {
            float v = bf2f(xs[tid * 16 + k]);
            big |= !(fabsf(v) < 1e10f);
        }
        unsigned long long m = __ballot(big);
        if (tid == 0) sflag = 0;
        __syncthreads();
        if ((tid & 63) == 0 && m != 0ull) sflag = 1;   // benign same-value race
        __syncthreads();
    }
    int f = sflag;
    if (bid == 0 && tid == 0) *flag = f;               // for gemm2's f32-out path

    if (bid < 8192) {                       // x: 8.4M elems, float4/ushort4 per thread
        int i = bid * 256 + tid;
        u16x4 o;
        if (f) {
            float4 v = ((const float4*)x)[i];
            o[0] = f2bf(v.x); o[1] = f2bf(v.y); o[2] = f2bf(v.z); o[3] = f2bf(v.w);
        } else {
            o = ((const u16x4*)x)[i];
        }
        ((u16x4*)xb)[i] = o;
    } else if (bid < 8208) {                // biases: 16 blocks x 256 = 4096
        int i = (bid - 8192) * 256 + tid;
        const void* src = (i < 1024) ? b0 : (i < 2048 ? b1 : (i < 3072 ? b2 : b3));
        int k = i & 1023;
        bb[i] = f ? f2bf(((const float*)src)[k]) : ((const unsigned short*)src)[k];
    } else {                                // weight transpose: 4 x 1024 tiles
        int tz = bid - 8208;
        int z = tz >> 10, tile = tz & 1023;
        const void* src = (z == 0) ? w0 : (z == 1 ? w1 : (z == 2 ? w2 : w3));
        unsigned short* dst = wT + (size_t)z * 1024 * 1024;
        int xx = tid & 31, yy = tid >> 5;   // 32 x 8
        int n0 = (tile & 31) * 32, k0 = (tile >> 5) * 32;
        for (int j = 0; j < 32; j += 8) {
            size_t idx = (size_t)(k0 + yy + j) * 1024 + n0 + xx;
            t[yy + j][xx] = f ? f2bf(((const float*)src)[idx]) : ((const unsigned short*)src)[idx];
        }
        __syncthreads();
        for (int j = 0; j < 32; j += 8) dst[(size_t)(n0 + yy + j) * 1024 + k0 + xx] = t[xx][yy + j];
    }
}

// ---- GEMM (128-tile, R7-proven pipelined schedule): C = A.Bt + bias ----
// LDS double-buffered; STAGE(t+1) issued BEFORE compute(t); ONE __syncthreads per K-step.
// XOR-swizzled LDS (slot = chunk ^ (row&7)), pre-swizzled global source.
// Block mapping: NATURAL (m0=x*128, n0=y*128). With gridDim.x=64 (64%8==0, x-fast dispatch),
// XCD = flat%8 = x%8 -> all blocks sharing an A-panel land on ONE XCD = perfect A-panel L2
// affinity (A fetched once, 16.8MB). R11's T1 swizzle broke this: FETCH 199.8MB (+133MB =
// A x8 XCDs), dur 74->87us. REVERTED. B-panel 8x spread (50MB) is topology-inherent.
// Coalesced V epilogue (kept from R11): transpose via dead As/Bs LDS -> 128B-contiguous vt
// stores; WRITE_SIZE ~70MB ~= data (was 8B-stores-at-4KB-stride line amplification).
__global__ __launch_bounds__(256) void gemm_bf16(const short* __restrict__ A,
                                                 const short* __restrict__ Bt,
                                                 void* __restrict__ C,
                                                 short* __restrict__ vt,
                                                 const unsigned short* __restrict__ bq,
                                                 const unsigned short* __restrict__ bk,
                                                 const unsigned short* __restrict__ bv,
                                                 int K, int ldc,
                                                 const int* __restrict__ flag, int f32out,
                                                 int scale_q, int fuse_v) {
    __shared__ __align__(16) short As[2][128][64];
    __shared__ __align__(16) short Bs[2][128][64];
    int tid = threadIdx.x;
    int wid = tid >> 6, lane = tid & 63, quad = lane >> 4, l16 = lane & 15;
    int wm = wid & 1, wn = wid >> 1;
    int m0 = blockIdx.x * 128, n0 = blockIdx.y * 128;
    bool wf = f32out && (*flag != 0);

    int srow = lane >> 3;                  // 0..7: row within the 8-row stage chunk
    int schunk = (lane & 7) ^ srow;        // pre-swizzled source chunk for this LDS slot
    const short* Ag = A  + (size_t)(m0 + wid * 32 + srow) * K + schunk * 8;
    const short* Bg = Bt + (size_t)(n0 + wid * 32 + srow) * K + schunk * 8;

    f32x4 acc[4][4] = {};
    int nt = K >> 6;

#pragma unroll
    for (int c = 0; c < 4; ++c) {
        gload_lds16(Ag + c * 8 * K, &As[0][wid * 32 + c * 8][0]);
        gload_lds16(Bg + c * 8 * K, &Bs[0][wid * 32 + c * 8][0]);
    }
    __syncthreads();

    for (int t = 0; t < nt; ++t) {
        if (t + 1 < nt) {                   // issue next-tile loads FIRST (hide under MFMA)
            int bu = (t + 1) & 1;
            int kof = (t + 1) * 64;
#pragma unroll
            for (int c = 0; c < 4; ++c) {
                gload_lds16(Ag + kof + c * 8 * K, &As[bu][wid * 32 + c * 8][0]);
                gload_lds16(Bg + kof + c * 8 * K, &Bs[bu][wid * 32 + c * 8][0]);
            }
        }
        const short (*Ab)[64] = As[t & 1];
#pragma unroll
        for (int kk = 0; kk < 2; ++kk) {    // two K=32 slices of the BK=64 tile
            s16x8 a[4], b[4];
#pragma unroll
            for (int i = 0; i < 4; ++i) {
                int row = wm * 64 + i * 16 + l16;
                a[i] = *(const s16x8*)&Ab[row][(((kk << 2) + quad) ^ (row & 7)) << 3];
            }
#pragma unroll
            for (int j = 0; j < 4; ++j) {
                int row = wn * 64 + j * 16 + l16;
                b[j] = *(const s16x8*)&Bs[t & 1][row][(((kk << 2) + quad) ^ (row & 7)) << 3];
            }
            __builtin_amdgcn_s_setprio(1);
#pragma unroll
            for (int i = 0; i < 4; ++i)
#pragma unroll
                for (int j = 0; j < 4; ++j)
                    acc[i][j] = __builtin_amdgcn_mfma_f32_16x16x32_bf16(a[i], b[j], acc[i][j], 0, 0, 0);
            __builtin_amdgcn_s_setprio(0);
        }
        __syncthreads();                    // single barrier/K-step: drains stage(t+1) + sync
    }

    if (fuse_v && n0 >= 2048) {
        // Whole tile is V. Transpose 128x128 via dead As/Bs (two 64x136 halves; 2-way write
        // conflicts = free). Then 128B-contiguous stores into vt[(b*16+h)*64+dk][t].
        short* vtl = (wn == 0) ? (short*)As : (short*)Bs;   // half by wn (cols 0-63 / 64-127)
#pragma unroll
        for (int j = 0; j < 4; ++j) {
            int c = j * 16 + l16;                           // dk within half
            float bias = bf2f(bv[(n0 - 2048) + wn * 64 + c]);
#pragma unroll
            for (int i = 0; i < 4; ++i) {
                int row = wm * 64 + i * 16 + quad * 4;      // t-local 0..127
                s16x4 pk;
                for (int r = 0; r < 4; ++r) pk[r] = (short)f2bf(acc[i][j][r] + bias);
                *(s16x4*)(vtl + c * 136 + row) = pk;
            }
        }
        __syncthreads();
        int sel = tid >> 7, t2 = tid & 127;                 // sel: which 64-col half
        int c = t2 >> 1, tc = (t2 & 1) * 64;                // dk row, 64-t chunk
        const short* vs = (sel ? (const short*)Bs : (const short*)As) + c * 136 + tc;
        int hgl = ((n0 - 2048) >> 6) + sel;
        int b_ = m0 >> 11;
        short* gdst = vt + ((size_t)((b_ * 16 + hgl) * 64 + c)) * 2048 + (m0 & 2047) + tc;
#pragma unroll
        for (int e = 0; e < 8; ++e)
            ((s16x8*)gdst)[e] = ((const s16x8*)vs)[e];      // 128B contiguous per thread
    } else {
        for (int j = 0; j < 4; ++j) {
            int col = n0 + wn * 64 + j * 16 + l16;
            const unsigned short* bptr = (col < 1024) ? bq : (col < 2048 ? bk : bv);
            float bias = bf2f(bptr[col & 1023]);
            float cs = (scale_q && col < 1024) ? 0.18033688f : 1.0f;   // 1/sqrt(64)*log2(e)
            for (int i = 0; i < 4; ++i) {
                int rbase = m0 + wm * 64 + i * 16 + quad * 4;
                for (int r = 0; r < 4; ++r) {
                    float v = (acc[i][j][r] + bias) * cs;
                    size_t idx = (size_t)(rbase + r) * ldc + col;
                    if (wf) ((float*)C)[idx] = v;
                    else    ((unsigned short*)C)[idx] = f2bf(v);
                }
            }
        }
    }
}

// ---- flash attention, counted-vmcnt pipeline (T3/T4) -- R7 form (85.4us measured) ----
static __device__ __forceinline__ void stage_tiles(const short* kbase, const short* vbase,
                                                   int kt, short* Kb, short* Vb,
                                                   int wid, int lane) {
    int row = wid * 8 + (lane >> 3);            // 0..63
    int c_src = (lane & 7) ^ (lane >> 3);       // source chunk for this slot
    const short* kg = kbase + (size_t)(kt * 64 + row) * 3072 + c_src * 8;
    const short* vg = vbase + (size_t)row * 2048 + kt * 64 + c_src * 8;
    gload_lds16(kg, Kb + wid * 512);            // wave-uniform LDS base + lane*16
    gload_lds16(vg, Vb + wid * 512);
}

static __device__ __forceinline__ s16x8 lds_frag(const short* buf, int row, int cg) {
    int slot = cg ^ (row & 7);
    return *(const s16x8*)(buf + row * 64 + slot * 8);
}

// grid (64, 16): x = bh, y -> qb = 15-y (heavy-first). 8 waves x 16 q-rows.
// K/V TRIPLE-buffered; ONE raw s_barrier per K-tile; counted s_waitcnt vmcnt(2).
// SWAPPED softmax (T12); T13 defer-max; raw v_exp_f32.
__global__ __launch_bounds__(512, 4) void attn(const short* __restrict__ qkv,
                                               const short* __restrict__ vt,
                                               unsigned short* __restrict__ y) {
    __shared__ __align__(16) short Kbuf[3][64 * 64];
    __shared__ __align__(16) short Vbuf[3][64 * 64];
    __shared__ __align__(16) short Ps[8][16 * 68];
    int tid = threadIdx.x;
    int wid = tid >> 6, lane = tid & 63, quad = lane >> 4, l16 = lane & 15;
    int bh = blockIdx.x, b = bh >> 4, h = bh & 15;
    const short* kbase = qkv + (size_t)b * 2048 * 3072 + 1024 + h * 64;
    const short* vbase = vt + (size_t)bh * 64 * 2048;
    short* PsW = &Ps[wid][0];

    s16x8 ones;
    for (int e = 0; e < 8; ++e) ones[e] = (short)0x3F80;   // bf16 1.0

    int qb = 15 - (int)blockIdx.y;              // heavy-first dispatch order
    int ktmax = 2 * qb + 1;
    int kmax_w = 2 * qb + (wid >> 2);           // causal limit for this wave's rows

    const short* qp = qkv + (size_t)(b * 2048 + qb * 128 + wid * 16 + l16) * 3072 + h * 64;
    s16x8 q0 = *(const s16x8*)(qp + quad * 8);
    s16x8 q1 = *(const s16x8*)(qp + 32 + quad * 8);

    float m_old = -INFINITY;                    // running max for q-row l16 (per-lane scalar)
    f32x4 lacc = {0.f, 0.f, 0.f, 0.f};
    f32x4 o[4] = {};

    stage_tiles(kbase, vbase, 0, &Kbuf[0][0], &Vbuf[0][0], wid, lane);
    stage_tiles(kbase, vbase, 1, &Kbuf[1][0], &Vbuf[1][0], wid, lane);
    int ss = 2;                                 // next stage slot
    int cc = 0;                                 // compute slot

    for (int kt = 0; kt <= ktmax; ++kt) {
        if (kt < ktmax) asm volatile("s_waitcnt vmcnt(2)" ::: "memory");
        else            asm volatile("s_waitcnt vmcnt(0)" ::: "memory");
        __builtin_amdgcn_sched_barrier(0);
        __builtin_amdgcn_s_barrier();

        if (kt + 2 <= ktmax) {
            stage_tiles(kbase, vbase, kt + 2, &Kbuf[0][0] + ss * 4096, &Vbuf[0][0] + ss * 4096,
                        wid, lane);
            ss = (ss == 2) ? 0 : ss + 1;
        }

        if (kt <= kmax_w) {                     // predicated compute; barriers stay uniform
            const short* Kb = &Kbuf[0][0] + cc * 4096;
            const short* Vb = &Vbuf[0][0] + cc * 4096;

            // S^T = K . Q^T  (A=K fragment, B=Q fragment: identical reg layouts, swapped roles)
            f32x4 s[4] = {};
            __builtin_amdgcn_s_setprio(1);
            for (int j = 0; j < 4; ++j) {
                s16x8 klo = lds_frag(Kb, j * 16 + l16, quad);
                s16x8 khi = lds_frag(Kb, j * 16 + l16, 4 + quad);
                s[j] = __builtin_amdgcn_mfma_f32_16x16x32_bf16(klo, q0, s[j], 0, 0, 0);
                s[j] = __builtin_amdgcn_mfma_f32_16x16x32_bf16(khi, q1, s[j], 0, 0, 0);
            }
            __builtin_amdgcn_s_setprio(0);

            if (kt == kmax_w) {                 // diagonal tile: mask k > q
                int qq = (wid & 3) * 16 + l16;  // q-row local to this 64-row k-tile span
                for (int j = 0; j < 4; ++j)
                    for (int r = 0; r < 4; ++r)
                        if (j * 16 + quad * 4 + r > qq) s[j][r] = -INFINITY;
            }

            // row-max: max3-friendly tree over 16 in-lane regs, then across the 4 quads
            float mj0 = fmaxf(fmaxf(s[0][0], s[0][1]), s[0][2]);   // v_max3
            mj0 = fmaxf(mj0, s[0][3]);
            float mj1 = fmaxf(fmaxf(s[1][0], s[1][1]), s[1][2]);
            mj1 = fmaxf(mj1, s[1][3]);
            float mj2 = fmaxf(fmaxf(s[2][0], s[2][1]), s[2][2]);
            mj2 = fmaxf(mj2, s[2][3]);
            float mj3 = fmaxf(fmaxf(s[3][0], s[3][1]), s[3][2]);
            mj3 = fmaxf(mj3, s[3][3]);
            float mx = fmaxf(fmaxf(fmaxf(mj0, mj1), mj2), mj3);
            mx = fmaxf(mx, __shfl_xor(mx, 16));
            mx = fmaxf(mx, __shfl_xor(mx, 32));

            // T13 defer-max: only rescale when some row grew by > 8 (log2 domain; P <= 256)
            if (__any(mx > m_old + 8.0f)) {
                float mn = fmaxf(m_old, mx);
                float alpha = fexp2(m_old - mn);    // 1 per lane
                m_old = mn;
                // O/lacc rows are quad*4+r (standard layout); alpha for row i lives in lane i
                float ar[4];
                for (int r = 0; r < 4; ++r) ar[r] = __shfl(alpha, quad * 4 + r);
                for (int r = 0; r < 4; ++r) {
                    lacc[r] *= ar[r];
                    for (int d = 0; d < 4; ++d) o[d][r] *= ar[r];
                }
            }

            // P = exp2(S - m): adjacent k in-lane -> packed bf16 pairs, one b64 store per j
            for (int j = 0; j < 4; ++j) {
                float p0 = fexp2(s[j][0] - m_old);
                float p1 = fexp2(s[j][1] - m_old);
                float p2 = fexp2(s[j][2] - m_old);
                float p3 = fexp2(s[j][3] - m_old);
                u32x2 w;
                w.x = cvt_pk_bf16(p0, p1);
                w.y = cvt_pk_bf16(p2, p3);
                *(u32x2*)(PsW + l16 * 68 + j * 16 + quad * 4) = w;   // P[q=l16][t=16j+4quad..+3]
            }

            // same-wave LDS RAW: DS ops program-ordered per wave
            s16x8 pa0 = *(const s16x8*)&PsW[l16 * 68 + quad * 8];
            s16x8 pa1 = *(const s16x8*)&PsW[l16 * 68 + 32 + quad * 8];
            __builtin_amdgcn_s_setprio(1);
            lacc = __builtin_amdgcn_mfma_f32_16x16x32_bf16(pa0, ones, lacc, 0, 0, 0);
            lacc = __builtin_amdgcn_mfma_f32_16x16x32_bf16(pa1, ones, lacc, 0, 0, 0);
            for (int d = 0; d < 4; ++d) {
                s16x8 vlo = lds_frag(Vb, d * 16 + l16, quad);
                s16x8 vhi = lds_frag(Vb, d * 16 + l16, 4 + quad);
                o[d] = __builtin_amdgcn_mfma_f32_16x16x32_bf16(pa0, vlo, o[d], 0, 0, 0);
                o[d] = __builtin_amdgcn_mfma_f32_16x16x32_bf16(pa1, vhi, o[d], 0, 0, 0);
            }
            __builtin_amdgcn_s_setprio(0);
        }
        cc = (cc == 2) ? 0 : cc + 1;
    }

    for (int r = 0; r < 4; ++r) {
        float inv = 1.f / lacc[r];
        int t = qb * 128 + wid * 16 + quad * 4 + r;
        for (int d = 0; d < 4; ++d)
            y[(size_t)(b * 2048 + t) * 1024 + h * 64 + d * 16 + l16] = f2bf(o[d][r] * inv);
    }
}

extern "C" void kernel_launch(void* const* d_in, const int* in_sizes, int n_in,
                              void* d_out, int out_size, void* d_ws, size_t ws_size,
                              hipStream_t stream) {
    (void)in_sizes; (void)n_in; (void)out_size; (void)ws_size;
    const void* x  = d_in[0];
    const void* wq = d_in[2]; const void* bq = d_in[3];
    const void* wk = d_in[4]; const void* bk = d_in[5];
    const void* wv = d_in[6]; const void* bv = d_in[7];
    const void* wo = d_in[8]; const void* bo = d_in[9];

    const size_t MB = 1024 * 1024;
    char* ws = (char*)d_ws;
    unsigned short* wT  = (unsigned short*)ws;                 // 4x[1024][1024] bf16  [0,8MB)
    short* qkv = (short*)(ws + 8 * MB);                        // [8192][3072] bf16    [8,56)
    short* vt  = (short*)(ws + 56 * MB);                       // [64][64][2048] bf16  [56,72)
    unsigned short* xb = (unsigned short*)(ws + 72 * MB);      // x as bf16 (aliases yb)
    unsigned short* yb = (unsigned short*)(ws + 72 * MB);      // attn out (after xb dead)
    unsigned short* bb = (unsigned short*)(ws + 88 * MB);      // 4x1024 bf16 biases
    int* flag = (int*)(ws + 88 * MB + 64 * 1024);

    prep<<<12304, 256, 0, stream>>>(x, bq, bk, bv, bo, wq, wk, wv, wo, xb, bb, wT, flag);

    gemm_bf16<<<dim3(64, 24), 256, 0, stream>>>((const short*)xb, (const short*)wT,
                                                qkv, vt, bb, bb + 1024, bb + 2048,
                                                1024, 3072, flag, 0, 1, 1);
    attn<<<dim3(64, 16), 512, 0, stream>>>(qkv, vt, yb);
    gemm_bf16<<<dim3(64, 8), 256, 0, stream>>>((const short*)yb, (const short*)(wT + 3072 * 1024),
                                               d_out, nullptr, bb + 3072, bb + 3072, bb + 3072,
                                               1024, 1024, flag, 1, 0, 0);
}

// Round 13
// 268.451 us; speedup vs baseline: 1.1372x; 1.0741x over previous
//
#include <hip/hip_runtime.h>

// MHA fwd: B=4, T=2048, D=1024, H=16, DK=64. Inputs/outputs f32 (flag-detected), compute bf16 MFMA.
// d_in: 0=x, 1=mask(ignored), 2=wq, 3=bq, 4=wk, 5=bk, 6=wv, 7=bv, 8=wo, 9=bo

typedef short s16x8 __attribute__((ext_vector_type(8)));
typedef short s16x4 __attribute__((ext_vector_type(4)));
typedef float f32x4 __attribute__((ext_vector_type(4)));
typedef unsigned int u32x2 __attribute__((ext_vector_type(2)));
typedef unsigned short u16x4 __attribute__((ext_vector_type(4)));

static __device__ __forceinline__ float bf2f(unsigned short u) {
    return __uint_as_float(((unsigned int)u) << 16);
}
static __device__ __forceinline__ unsigned short f2bf(float f) {
    unsigned int x = __float_as_uint(f);
    unsigned int r = x + 0x7fffu + ((x >> 16) & 1u);  // RTNE
    return (unsigned short)(r >> 16);
}

static __device__ __forceinline__ void gload_lds16(const short* g, short* l) {
    __builtin_amdgcn_global_load_lds((__attribute__((address_space(1))) void*)g,
                                     (__attribute__((address_space(3))) void*)l, 16, 0, 0);
}

// packed f32x2 -> bf16x2 (RTNE); src0 -> low 16 bits
static __device__ __forceinline__ unsigned int cvt_pk_bf16(float a, float b) {
    unsigned int r;
    asm("v_cvt_pk_bf16_f32 %0, %1, %2" : "=v"(r) : "v"(a), "v"(b));
    return r;
}

// raw v_exp_f32 (exp2): libm exp2f w/o fast-math emits ~7 extra VALU ops of denorm/range
// fixup per call; attention P in [0,2^8] only needs flush-to-zero semantics. -inf -> 0.
static __device__ __forceinline__ float fexp2(float x) {
    float r;
    asm("v_exp_f32 %0, %1" : "=v"(r) : "v"(x));
    return r;
}

// ---- fused prep: dtype-detect (per-block, redundant, L2-broadcast) + x-convert (x8 vec)
//      + biases + 4 weight transposes, ONE launch; block 0 publishes flag for gemm2 ----
// blocks [0,4096): x, 8 elems/thread; [4096,4112): biases; [4112,8208): transpose tiles.
__global__ __launch_bounds__(256) void prep(const void* __restrict__ x,
                                            const void* __restrict__ b0, const void* __restrict__ b1,
                                            const void* __restrict__ b2, const void* __restrict__ b3,
                                            const void* __restrict__ w0, const void* __restrict__ w1,
                                            const void* __restrict__ w2, const void* __restrict__ w3,
                                            unsigned short* __restrict__ xb,
                                            unsigned short* __restrict__ bb,
                                            unsigned short* __restrict__ wT,
                                            int* __restrict__ flag) {
    __shared__ unsigned short t[32][33];
    __shared__ int sflag;
    int bid = blockIdx.x, tid = threadIdx.x;

    // detect: 1024 ushort samples of x. f32 input -> even ushorts are mantissa-low bits,
    // ~37% of which decode as |bf16|>=1e10; P(miss over 512 such samples) ~ 0.
    {
        const unsigned short* xs = (const unsigned short*)x;
        bool big = false;
        for (int k = 0; k < 4; ++k) {
            float v = bf2f(xs[tid * 4 + k]);
            big |= !(fabsf(v) < 1e10f);
        }
        unsigned long long m = __ballot(big);
        if (tid == 0) sflag = 0;
        __syncthreads();
        if ((tid & 63) == 0 && m != 0ull) sflag = 1;   // benign same-value race
        __syncthreads();
    }
    int f = sflag;
    if (bid == 0 && tid == 0) *flag = f;               // for gemm2's f32-out path

    if (bid < 4096) {                       // x: 8.4M elems, 8 per thread (2xfloat4 -> s16x8)
        int i = bid * 256 + tid;
        if (f) {
            float4 v0 = ((const float4*)x)[2 * i];
            float4 v1 = ((const float4*)x)[2 * i + 1];
            s16x8 o;
            o[0] = (short)f2bf(v0.x); o[1] = (short)f2bf(v0.y);
            o[2] = (short)f2bf(v0.z); o[3] = (short)f2bf(v0.w);
            o[4] = (short)f2bf(v1.x); o[5] = (short)f2bf(v1.y);
            o[6] = (short)f2bf(v1.z); o[7] = (short)f2bf(v1.w);
            ((s16x8*)xb)[i] = o;
        } else {
            ((s16x8*)xb)[i] = ((const s16x8*)x)[i];
        }
    } else if (bid < 4112) {                // biases: 16 blocks x 256 = 4096
        int i = (bid - 4096) * 256 + tid;
        const void* src = (i < 1024) ? b0 : (i < 2048 ? b1 : (i < 3072 ? b2 : b3));
        int k = i & 1023;
        bb[i] = f ? f2bf(((const float*)src)[k]) : ((const unsigned short*)src)[k];
    } else {                                // weight transpose: 4 x 1024 tiles
        int tz = bid - 4112;
        int z = tz >> 10, tile = tz & 1023;
        const void* src = (z == 0) ? w0 : (z == 1 ? w1 : (z == 2 ? w2 : w3));
        unsigned short* dst = wT + (size_t)z * 1024 * 1024;
        int xx = tid & 31, yy = tid >> 5;   // 32 x 8
        int n0 = (tile & 31) * 32, k0 = (tile >> 5) * 32;
        for (int j = 0; j < 32; j += 8) {
            size_t idx = (size_t)(k0 + yy + j) * 1024 + n0 + xx;
            t[yy + j][xx] = f ? f2bf(((const float*)src)[idx]) : ((const unsigned short*)src)[idx];
        }
        __syncthreads();
        for (int j = 0; j < 32; j += 8) dst[(size_t)(n0 + yy + j) * 1024 + k0 + xx] = t[xx][yy + j];
    }
}

// ---- GEMM (128-tile, R7-proven pipelined schedule): C = A.Bt + bias ----
// LDS double-buffered; STAGE(t+1) issued BEFORE compute(t); ONE __syncthreads per K-step.
// XOR-swizzled LDS (slot = chunk ^ (row&7)), pre-swizzled global source.
// Block mapping: NATURAL (m0=x*128, n0=y*128). With gridDim.x=64 (64%8==0, x-fast dispatch),
// XCD = flat%8 = x%8 -> all blocks sharing an A-panel land on ONE XCD = perfect A-panel L2
// affinity (A fetched once). R11's T1 swizzle broke this (FETCH 199.8MB): REVERTED.
// Coalesced V epilogue: transpose via dead As/Bs LDS -> 128B-contiguous vt stores.
__global__ __launch_bounds__(256) void gemm_bf16(const short* __restrict__ A,
                                                 const short* __restrict__ Bt,
                                                 void* __restrict__ C,
                                                 short* __restrict__ vt,
                                                 const unsigned short* __restrict__ bq,
                                                 const unsigned short* __restrict__ bk,
                                                 const unsigned short* __restrict__ bv,
                                                 int K, int ldc,
                                                 const int* __restrict__ flag, int f32out,
                                                 int scale_q, int fuse_v) {
    __shared__ __align__(16) short As[2][128][64];
    __shared__ __align__(16) short Bs[2][128][64];
    int tid = threadIdx.x;
    int wid = tid >> 6, lane = tid & 63, quad = lane >> 4, l16 = lane & 15;
    int wm = wid & 1, wn = wid >> 1;
    int m0 = blockIdx.x * 128, n0 = blockIdx.y * 128;
    bool wf = f32out && (*flag != 0);

    int srow = lane >> 3;                  // 0..7: row within the 8-row stage chunk
    int schunk = (lane & 7) ^ srow;        // pre-swizzled source chunk for this LDS slot
    const short* Ag = A  + (size_t)(m0 + wid * 32 + srow) * K + schunk * 8;
    const short* Bg = Bt + (size_t)(n0 + wid * 32 + srow) * K + schunk * 8;

    f32x4 acc[4][4] = {};
    int nt = K >> 6;

#pragma unroll
    for (int c = 0; c < 4; ++c) {
        gload_lds16(Ag + c * 8 * K, &As[0][wid * 32 + c * 8][0]);
        gload_lds16(Bg + c * 8 * K, &Bs[0][wid * 32 + c * 8][0]);
    }
    __syncthreads();

    for (int t = 0; t < nt; ++t) {
        if (t + 1 < nt) {                   // issue next-tile loads FIRST (hide under MFMA)
            int bu = (t + 1) & 1;
            int kof = (t + 1) * 64;
#pragma unroll
            for (int c = 0; c < 4; ++c) {
                gload_lds16(Ag + kof + c * 8 * K, &As[bu][wid * 32 + c * 8][0]);
                gload_lds16(Bg + kof + c * 8 * K, &Bs[bu][wid * 32 + c * 8][0]);
            }
        }
        const short (*Ab)[64] = As[t & 1];
#pragma unroll
        for (int kk = 0; kk < 2; ++kk) {    // two K=32 slices of the BK=64 tile
            s16x8 a[4], b[4];
#pragma unroll
            for (int i = 0; i < 4; ++i) {
                int row = wm * 64 + i * 16 + l16;
                a[i] = *(const s16x8*)&Ab[row][(((kk << 2) + quad) ^ (row & 7)) << 3];
            }
#pragma unroll
            for (int j = 0; j < 4; ++j) {
                int row = wn * 64 + j * 16 + l16;
                b[j] = *(const s16x8*)&Bs[t & 1][row][(((kk << 2) + quad) ^ (row & 7)) << 3];
            }
            __builtin_amdgcn_s_setprio(1);
#pragma unroll
            for (int i = 0; i < 4; ++i)
#pragma unroll
                for (int j = 0; j < 4; ++j)
                    acc[i][j] = __builtin_amdgcn_mfma_f32_16x16x32_bf16(a[i], b[j], acc[i][j], 0, 0, 0);
            __builtin_amdgcn_s_setprio(0);
        }
        __syncthreads();                    // single barrier/K-step: drains stage(t+1) + sync
    }

    if (fuse_v && n0 >= 2048) {
        // Whole tile is V. Transpose 128x128 via dead As/Bs (two 64x136 halves; 2-way write
        // conflicts = free). Then 128B-contiguous stores into vt[(b*16+h)*64+dk][t].
        short* vtl = (wn == 0) ? (short*)As : (short*)Bs;   // half by wn (cols 0-63 / 64-127)
#pragma unroll
        for (int j = 0; j < 4; ++j) {
            int c = j * 16 + l16;                           // dk within half
            float bias = bf2f(bv[(n0 - 2048) + wn * 64 + c]);
#pragma unroll
            for (int i = 0; i < 4; ++i) {
                int row = wm * 64 + i * 16 + quad * 4;      // t-local 0..127
                s16x4 pk;
                for (int r = 0; r < 4; ++r) pk[r] = (short)f2bf(acc[i][j][r] + bias);
                *(s16x4*)(vtl + c * 136 + row) = pk;
            }
        }
        __syncthreads();
        int sel = tid >> 7, t2 = tid & 127;                 // sel: which 64-col half
        int c = t2 >> 1, tc = (t2 & 1) * 64;                // dk row, 64-t chunk
        const short* vs = (sel ? (const short*)Bs : (const short*)As) + c * 136 + tc;
        int hgl = ((n0 - 2048) >> 6) + sel;
        int b_ = m0 >> 11;
        short* gdst = vt + ((size_t)((b_ * 16 + hgl) * 64 + c)) * 2048 + (m0 & 2047) + tc;
#pragma unroll
        for (int e = 0; e < 8; ++e)
            ((s16x8*)gdst)[e] = ((const s16x8*)vs)[e];      // 128B contiguous per thread
    } else {
        for (int j = 0; j < 4; ++j) {
            int col = n0 + wn * 64 + j * 16 + l16;
            const unsigned short* bptr = (col < 1024) ? bq : (col < 2048 ? bk : bv);
            float bias = bf2f(bptr[col & 1023]);
            float cs = (scale_q && col < 1024) ? 0.18033688f : 1.0f;   // 1/sqrt(64)*log2(e)
            for (int i = 0; i < 4; ++i) {
                int rbase = m0 + wm * 64 + i * 16 + quad * 4;
                for (int r = 0; r < 4; ++r) {
                    float v = (acc[i][j][r] + bias) * cs;
                    size_t idx = (size_t)(rbase + r) * ldc + col;
                    if (wf) ((float*)C)[idx] = v;
                    else    ((unsigned short*)C)[idx] = f2bf(v);
                }
            }
        }
    }
}

// ---- flash attention, counted-vmcnt pipeline (T3/T4) -- R7 form (85.4us measured) ----
static __device__ __forceinline__ void stage_tiles(const short* kbase, const short* vbase,
                                                   int kt, short* Kb, short* Vb,
                                                   int wid, int lane) {
    int row = wid * 8 + (lane >> 3);            // 0..63
    int c_src = (lane & 7) ^ (lane >> 3);       // source chunk for this slot
    const short* kg = kbase + (size_t)(kt * 64 + row) * 3072 + c_src * 8;
    const short* vg = vbase + (size_t)row * 2048 + kt * 64 + c_src * 8;
    gload_lds16(kg, Kb + wid * 512);            // wave-uniform LDS base + lane*16
    gload_lds16(vg, Vb + wid * 512);
}

static __device__ __forceinline__ s16x8 lds_frag(const short* buf, int row, int cg) {
    int slot = cg ^ (row & 7);
    return *(const s16x8*)(buf + row * 64 + slot * 8);
}

// grid (64, 16): x = bh, y -> qb = 15-y (heavy-first). 8 waves x 16 q-rows.
// K/V TRIPLE-buffered; ONE raw s_barrier per K-tile; counted s_waitcnt vmcnt(2).
// SWAPPED softmax (T12); T13 defer-max; raw v_exp_f32.
// Ps stride 72 (was 68): keeps every b128 row access 16B-aligned so the o-epilogue can be
// staged through Ps and stored as 2xb128 per lane (replaces 16 scalar b16 global stores).
__global__ __launch_bounds__(512, 4) void attn(const short* __restrict__ qkv,
                                               const short* __restrict__ vt,
                                               unsigned short* __restrict__ y) {
    __shared__ __align__(16) short Kbuf[3][64 * 64];
    __shared__ __align__(16) short Vbuf[3][64 * 64];
    __shared__ __align__(16) short Ps[8][16 * 72];
    int tid = threadIdx.x;
    int wid = tid >> 6, lane = tid & 63, quad = lane >> 4, l16 = lane & 15;
    int bh = blockIdx.x, b = bh >> 4, h = bh & 15;
    const short* kbase = qkv + (size_t)b * 2048 * 3072 + 1024 + h * 64;
    const short* vbase = vt + (size_t)bh * 64 * 2048;
    short* PsW = &Ps[wid][0];

    s16x8 ones;
    for (int e = 0; e < 8; ++e) ones[e] = (short)0x3F80;   // bf16 1.0

    int qb = 15 - (int)blockIdx.y;              // heavy-first dispatch order
    int ktmax = 2 * qb + 1;
    int kmax_w = 2 * qb + (wid >> 2);           // causal limit for this wave's rows

    const short* qp = qkv + (size_t)(b * 2048 + qb * 128 + wid * 16 + l16) * 3072 + h * 64;
    s16x8 q0 = *(const s16x8*)(qp + quad * 8);
    s16x8 q1 = *(const s16x8*)(qp + 32 + quad * 8);

    float m_old = -INFINITY;                    // running max for q-row l16 (per-lane scalar)
    f32x4 lacc = {0.f, 0.f, 0.f, 0.f};
    f32x4 o[4] = {};

    stage_tiles(kbase, vbase, 0, &Kbuf[0][0], &Vbuf[0][0], wid, lane);
    stage_tiles(kbase, vbase, 1, &Kbuf[1][0], &Vbuf[1][0], wid, lane);
    int ss = 2;                                 // next stage slot
    int cc = 0;                                 // compute slot

    for (int kt = 0; kt <= ktmax; ++kt) {
        if (kt < ktmax) asm volatile("s_waitcnt vmcnt(2)" ::: "memory");
        else            asm volatile("s_waitcnt vmcnt(0)" ::: "memory");
        __builtin_amdgcn_sched_barrier(0);
        __builtin_amdgcn_s_barrier();

        if (kt + 2 <= ktmax) {
            stage_tiles(kbase, vbase, kt + 2, &Kbuf[0][0] + ss * 4096, &Vbuf[0][0] + ss * 4096,
                        wid, lane);
            ss = (ss == 2) ? 0 : ss + 1;
        }

        if (kt <= kmax_w) {                     // predicated compute; barriers stay uniform
            const short* Kb = &Kbuf[0][0] + cc * 4096;
            const short* Vb = &Vbuf[0][0] + cc * 4096;

            // S^T = K . Q^T  (A=K fragment, B=Q fragment: identical reg layouts, swapped roles)
            f32x4 s[4] = {};
            __builtin_amdgcn_s_setprio(1);
            for (int j = 0; j < 4; ++j) {
                s16x8 klo = lds_frag(Kb, j * 16 + l16, quad);
                s16x8 khi = lds_frag(Kb, j * 16 + l16, 4 + quad);
                s[j] = __builtin_amdgcn_mfma_f32_16x16x32_bf16(klo, q0, s[j], 0, 0, 0);
                s[j] = __builtin_amdgcn_mfma_f32_16x16x32_bf16(khi, q1, s[j], 0, 0, 0);
            }
            __builtin_amdgcn_s_setprio(0);

            if (kt == kmax_w) {                 // diagonal tile: mask k > q
                int qq = (wid & 3) * 16 + l16;  // q-row local to this 64-row k-tile span
                for (int j = 0; j < 4; ++j)
                    for (int r = 0; r < 4; ++r)
                        if (j * 16 + quad * 4 + r > qq) s[j][r] = -INFINITY;
            }

            // row-max: max3-friendly tree over 16 in-lane regs, then across the 4 quads
            float mj0 = fmaxf(fmaxf(s[0][0], s[0][1]), s[0][2]);   // v_max3
            mj0 = fmaxf(mj0, s[0][3]);
            float mj1 = fmaxf(fmaxf(s[1][0], s[1][1]), s[1][2]);
            mj1 = fmaxf(mj1, s[1][3]);
            float mj2 = fmaxf(fmaxf(s[2][0], s[2][1]), s[2][2]);
            mj2 = fmaxf(mj2, s[2][3]);
            float mj3 = fmaxf(fmaxf(s[3][0], s[3][1]), s[3][2]);
            mj3 = fmaxf(mj3, s[3][3]);
            float mx = fmaxf(fmaxf(fmaxf(mj0, mj1), mj2), mj3);
            mx = fmaxf(mx, __shfl_xor(mx, 16));
            mx = fmaxf(mx, __shfl_xor(mx, 32));

            // T13 defer-max: only rescale when some row grew by > 8 (log2 domain; P <= 256)
            if (__any(mx > m_old + 8.0f)) {
                float mn = fmaxf(m_old, mx);
                float alpha = fexp2(m_old - mn);    // 1 per lane
                m_old = mn;
                // O/lacc rows are quad*4+r (standard layout); alpha for row i lives in lane i
                float ar[4];
                for (int r = 0; r < 4; ++r) ar[r] = __shfl(alpha, quad * 4 + r);
                for (int r = 0; r < 4; ++r) {
                    lacc[r] *= ar[r];
                    for (int d = 0; d < 4; ++d) o[d][r] *= ar[r];
                }
            }

            // P = exp2(S - m): adjacent k in-lane -> packed bf16 pairs, one b64 store per j
            for (int j = 0; j < 4; ++j) {
                float p0 = fexp2(s[j][0] - m_old);
                float p1 = fexp2(s[j][1] - m_old);
                float p2 = fexp2(s[j][2] - m_old);
                float p3 = fexp2(s[j][3] - m_old);
                u32x2 w;
                w.x = cvt_pk_bf16(p0, p1);
                w.y = cvt_pk_bf16(p2, p3);
                *(u32x2*)(PsW + l16 * 72 + j * 16 + quad * 4) = w;   // P[q=l16][t=16j+4quad..+3]
            }

            // same-wave LDS RAW: DS ops program-ordered per wave
            s16x8 pa0 = *(const s16x8*)&PsW[l16 * 72 + quad * 8];
            s16x8 pa1 = *(const s16x8*)&PsW[l16 * 72 + 32 + quad * 8];
            __builtin_amdgcn_s_setprio(1);
            lacc = __builtin_amdgcn_mfma_f32_16x16x32_bf16(pa0, ones, lacc, 0, 0, 0);
            lacc = __builtin_amdgcn_mfma_f32_16x16x32_bf16(pa1, ones, lacc, 0, 0, 0);
            for (int d = 0; d < 4; ++d) {
                s16x8 vlo = lds_frag(Vb, d * 16 + l16, quad);
                s16x8 vhi = lds_frag(Vb, d * 16 + l16, 4 + quad);
                o[d] = __builtin_amdgcn_mfma_f32_16x16x32_bf16(pa0, vlo, o[d], 0, 0, 0);
                o[d] = __builtin_amdgcn_mfma_f32_16x16x32_bf16(pa1, vhi, o[d], 0, 0, 0);
            }
            __builtin_amdgcn_s_setprio(0);
        }
        cc = (cc == 2) ? 0 : cc + 1;
    }

    // vectorized epilogue: stage o (bf16, / lacc) into this wave's Ps rows, then 2xb128/lane.
    // Same-wave cross-lane LDS RAW: DS ops program-ordered per wave; compiler inserts lgkmcnt.
    for (int r = 0; r < 4; ++r) {
        float inv = 1.f / lacc[r];
        for (int d = 0; d < 4; ++d)
            PsW[(quad * 4 + r) * 72 + d * 16 + l16] = (short)f2bf(o[d][r] * inv);
    }
    {
        int row = lane >> 2, cg = lane & 3;     // 16 rows x 2 16B-chunks per lane
        int trow = qb * 128 + wid * 16 + row;
        size_t ybase = (size_t)(b * 2048 + trow) * 1024 + h * 64;
        *(s16x8*)&y[ybase + cg * 8]      = *(const s16x8*)(PsW + row * 72 + cg * 8);
        *(s16x8*)&y[ybase + 32 + cg * 8] = *(const s16x8*)(PsW + row * 72 + 32 + cg * 8);
    }
}

extern "C" void kernel_launch(void* const* d_in, const int* in_sizes, int n_in,
                              void* d_out, int out_size, void* d_ws, size_t ws_size,
                              hipStream_t stream) {
    (void)in_sizes; (void)n_in; (void)out_size; (void)ws_size;
    const void* x  = d_in[0];
    const void* wq = d_in[2]; const void* bq = d_in[3];
    const void* wk = d_in[4]; const void* bk = d_in[5];
    const void* wv = d_in[6]; const void* bv = d_in[7];
    const void* wo = d_in[8]; const void* bo = d_in[9];

    const size_t MB = 1024 * 1024;
    char* ws = (char*)d_ws;
    unsigned short* wT  = (unsigned short*)ws;                 // 4x[1024][1024] bf16  [0,8MB)
    short* qkv = (short*)(ws + 8 * MB);                        // [8192][3072] bf16    [8,56)
    short* vt  = (short*)(ws + 56 * MB);                       // [64][64][2048] bf16  [56,72)
    unsigned short* xb = (unsigned short*)(ws + 72 * MB);      // x as bf16 (aliases yb)
    unsigned short* yb = (unsigned short*)(ws + 72 * MB);      // attn out (after xb dead)
    unsigned short* bb = (unsigned short*)(ws + 88 * MB);      // 4x1024 bf16 biases
    int* flag = (int*)(ws + 88 * MB + 64 * 1024);

    prep<<<8208, 256, 0, stream>>>(x, bq, bk, bv, bo, wq, wk, wv, wo, xb, bb, wT, flag);

    gemm_bf16<<<dim3(64, 24), 256, 0, stream>>>((const short*)xb, (const short*)wT,
                                                qkv, vt, bb, bb + 1024, bb + 2048,
                                                1024, 3072, flag, 0, 1, 1);
    attn<<<dim3(64, 16), 512, 0, stream>>>(qkv, vt, yb);
    gemm_bf16<<<dim3(64, 8), 256, 0, stream>>>((const short*)yb, (const short*)(wT + 3072 * 1024),
                                               d_out, nullptr, bb + 3072, bb + 3072, bb + 3072,
                                               1024, 1024, flag, 1, 0, 0);
}